// Round 12
// baseline (13603.433 us; speedup 1.0000x reference)
//
#include <hip/hip_runtime.h>
#include <stdint.h>

// Problem: D-FPS. points_xyz (16, 131072, 3) fp32 -> indices (16, 4096) int32.
//
// Round 12: BATCH PAIRING. r8's flat relaxed protocol (best, 9603 us) has a
// ~1.5 us/iter serialized sync chain (~1 L3 RT + reduce/fanout) that r9-r11
// proved untunable from inside. The batches are independent, so each block
// now owns chunks of TWO batches (A,B; both LDS-resident) and the loop is
// software-pipelined so A's publish->poll RT is in flight during B's update
// and vice versa:
//   body(it): updA -> gsA(it) | resolveB(it-1) | updB -> gsB(it) | resolveA(it)
// Per-CU update work per body = r8's per-iter work (same 8192 pts), so the
// update cost is unchanged and the RT hides under it.
// Locked-in lessons: relaxed-only agent atomics, tag+payload in one 64-bit
// word (r7/r8); ONE polling wave per block (r5/r10); points in LDS SoA
// (r3-r5); FMA-chain distance, exact-rounded subs (r2, bit-exact).

#define BATCH 16
#define NPTS  131072
#define NSAMP 4096
#define NPAIR 8                   // batch pairs
#define NBLK  32                  // blocks per pair (= per batch)
#define TPB   512                 // 8 waves
#define CHUNK (NPTS / NBLK)       // 4096 points per block per batch
#define PPT   (CHUNK / TPB)       // 8 points per thread per batch
#define NWAVE (TPB / 64)          // 8

typedef unsigned long long u64;
typedef unsigned int u32;

// Slot word (8B): [63:32] dist bits | [31:15] idx (17b) | [14:0] iter tag.
// Poison 0xAA.. -> tag 0x2AAA; zero-init -> 0; live tags 1..4095.
// Ring-2 by parity per batch; audit: block X overwrites gs*(par) at it+2
// only after its poll of it+1, which needs every block's publish of it+1,
// which (program order) follows that block's completed poll of it.

__global__ void fps_init_kernel(u64* __restrict__ ws) {
    int i = blockIdx.x * blockDim.x + threadIdx.x;
    if (i < NPAIR * 2 * 2 * NBLK) ws[i] = 0ull;    // 1024 words
}

__global__ __launch_bounds__(TPB, 2) void fps_kernel(
        const float* __restrict__ xyz, int* __restrict__ out,
        u64* __restrict__ gslot) {
    const int blk   = blockIdx.x;
    const int pair  = blk & 7;     // a pair's 32 blocks share blk%8 (XCD aff.)
    const int chunk = blk >> 3;
    const int tid   = threadIdx.x;
    const int w     = tid >> 6;
    const int lane  = tid & 63;

    const int bA = pair * 2, bB = pair * 2 + 1;
    const float* xyzA = xyz + (size_t)bA * NPTS * 3;
    const float* xyzB = xyz + (size_t)bB * NPTS * 3;
    const int base = chunk * CHUNK;

    u64* gsA = gslot + ((size_t)pair * 2 + 0) * 2 * NBLK;  // [2][NBLK]
    u64* gsB = gslot + ((size_t)pair * 2 + 1) * 2 * NBLK;

    // ---- LDS: both batches' points (SoA) + sync words (~96.6 KB) ----
    __shared__ float2 sxyA[CHUNK];         // 32 KB
    __shared__ float  szA [CHUNK];         // 16 KB
    __shared__ float2 sxyB[CHUNK];         // 32 KB
    __shared__ float  szB [CHUNK];         // 16 KB
    __shared__ u64 redA[2][NWAVE], redB[2][NWAVE];
    __shared__ u64 bcA[2], bcB[2];
    for (int i = tid; i < CHUNK; i += TPB) {
        size_t p = (size_t)(base + i) * 3;
        sxyA[i] = make_float2(xyzA[p + 0], xyzA[p + 1]);
        szA[i]  = xyzA[p + 2];
        sxyB[i] = make_float2(xyzB[p + 0], xyzB[p + 1]);
        szB[i]  = xyzB[p + 2];
    }
    if (tid < NWAVE) {
        redA[0][tid] = ~0ull; redA[1][tid] = ~0ull;   // tag 0x7FFF: invalid
        redB[0][tid] = ~0ull; redB[1][tid] = ~0ull;
    }
    if (tid < 2) { bcA[tid] = ~0ull; bcB[tid] = ~0ull; }  // low32 invalid
    if (tid == 0 && chunk == 0) { out[bA * NSAMP] = 0; out[bB * NSAMP] = 0; }
    __syncthreads();   // staging visibility (only block-wide barrier)

    float pdA[PPT], pdB[PPT];
#pragma unroll
    for (int k = 0; k < PPT; ++k) { pdA[k] = __builtin_inff(); pdB[k] = __builtin_inff(); }

    float cxA = xyzA[0], cyA = xyzA[1], czA = xyzA[2];
    float cxB = xyzB[0], cyB = xyzB[1], czB = xyzB[2];

    // Verified arithmetic (r2, absmax 0): d = fma(dz,dz, fma(dy,dy, dx*dx)),
    // subs exact-rounded; strict > keeps earliest k (first-occurrence).
#define UPDATE(SXY, SZ, PD, CX, CY, CZ, KEYOUT)                               \
    {                                                                          \
        float bd = -1.0f; int bk = 0;                                          \
        _Pragma("unroll")                                                      \
        for (int k = 0; k < PPT; ++k) {                                        \
            int i = tid + TPB * k;                                             \
            float2 xy = SXY[i]; float z = SZ[i];                               \
            float dx = __fsub_rn(xy.x, CX);                                    \
            float dy = __fsub_rn(xy.y, CY);                                    \
            float dz = __fsub_rn(z,    CZ);                                    \
            float d  = __builtin_fmaf(dz, dz,                                  \
                         __builtin_fmaf(dy, dy, __fmul_rn(dx, dx)));           \
            float nd = fminf(PD[k], d);                                        \
            PD[k] = nd;                                                        \
            if (nd > bd) { bd = nd; bk = k; }                                  \
        }                                                                      \
        u32 gi = (u32)(base + tid + TPB * bk);                                 \
        KEYOUT = ((u64)__float_as_uint(bd) << 32) | (u64)(~gi);                \
        _Pragma("unroll")                                                      \
        for (int off = 1; off <= 32; off <<= 1) {                              \
            u64 o = __shfl_xor(KEYOUT, off, 64);                               \
            KEYOUT = KEYOUT > o ? KEYOUT : o;                                  \
        }                                                                      \
    }

    // wave0: poll this block's 8 red entries (tagged IT), combine, publish.
#define COMBINE_PUBLISH(RED, GSP, PAR, IT)                                     \
    {                                                                          \
        u64 v; bool ok;                                                        \
        do {                                                                   \
            v  = (lane < NWAVE)                                                \
                   ? __hip_atomic_load(&RED[PAR][lane], __ATOMIC_RELAXED,      \
                                       __HIP_MEMORY_SCOPE_WORKGROUP)           \
                   : 0ull;                                                     \
            ok = (lane < NWAVE) ? ((v & 0x7FFFull) == (u64)(IT)) : true;       \
        } while (__ballot(ok) != ~0ull);                                       \
        u64 k2 = 0ull;                                                         \
        if (lane < NWAVE) {                                                    \
            u32 db  = (u32)(v >> 32);                                          \
            u32 idx = (u32)((v >> 15) & 0x1FFFFu);                             \
            k2 = ((u64)db << 32) | (u64)(~idx);                                \
        }                                                                      \
        _Pragma("unroll")                                                      \
        for (int off = 1; off <= 4; off <<= 1) {                               \
            u64 o = __shfl_xor(k2, off, 64);                                   \
            k2 = k2 > o ? k2 : o;                                              \
        }                                                                      \
        if (lane == 0) {                                                       \
            u32 db  = (u32)(k2 >> 32);                                         \
            u32 idx = ~(u32)k2;                                                \
            __hip_atomic_store(&GSP[chunk],                                    \
                ((u64)db << 32) | ((u64)idx << 15) | (u64)(IT),                \
                __ATOMIC_RELAXED, __HIP_MEMORY_SCOPE_AGENT);                   \
        }                                                                      \
    }

    // wave0: poll all 32 slot words (tagged IT), butterfly, out+bc fanout.
#define RESOLVE_W0(GSP, BC, PAR, IT, BROW, XP, CX, CY, CZ)                     \
    {                                                                          \
        u64 v; bool ok;                                                        \
        do {                                                                   \
            v  = (lane < NBLK)                                                 \
                   ? __hip_atomic_load(&GSP[lane], __ATOMIC_RELAXED,           \
                                       __HIP_MEMORY_SCOPE_AGENT)               \
                   : 0ull;                                                     \
            ok = (lane < NBLK) ? ((v & 0x7FFFull) == (u64)(IT)) : true;        \
        } while (__ballot(ok) != ~0ull);                                       \
        u64 k3 = 0ull;                                                         \
        if (lane < NBLK) {                                                     \
            u32 db  = (u32)(v >> 32);                                          \
            u32 idx = (u32)((v >> 15) & 0x1FFFFu);                             \
            k3 = ((u64)db << 32) | (u64)(~idx);                                \
        }                                                                      \
        _Pragma("unroll")                                                      \
        for (int off = 1; off <= 32; off <<= 1) {                              \
            u64 o = __shfl_xor(k3, off, 64);                                   \
            k3 = k3 > o ? k3 : o;                                              \
        }                                                                      \
        u32 widx = ~(u32)k3;                                                   \
        if (lane == 0) {                                                       \
            if (chunk == 0) out[(BROW) * NSAMP + (IT)] = (int)widx;            \
            __hip_atomic_store(&BC[PAR], ((u64)widx << 32) | (u64)(u32)(IT),   \
                __ATOMIC_RELAXED, __HIP_MEMORY_SCOPE_WORKGROUP);               \
        }                                                                      \
        CX = XP[3 * (size_t)widx + 0];                                         \
        CY = XP[3 * (size_t)widx + 1];                                         \
        CZ = XP[3 * (size_t)widx + 2];                                         \
    }

    // followers: wait for tagged bc, load coords (same-address broadcast).
#define RESOLVE_FOLLOW(BC, PAR, IT, XP, CX, CY, CZ)                            \
    {                                                                          \
        u64 bv;                                                                \
        do {                                                                   \
            bv = __hip_atomic_load(&BC[PAR], __ATOMIC_RELAXED,                 \
                                   __HIP_MEMORY_SCOPE_WORKGROUP);              \
        } while ((u32)bv != (u32)(IT));                                        \
        u32 widx = (u32)(bv >> 32);                                            \
        CX = XP[3 * (size_t)widx + 0];                                         \
        CY = XP[3 * (size_t)widx + 1];                                         \
        CZ = XP[3 * (size_t)widx + 2];                                         \
    }

    for (int it = 1; it < NSAMP; ++it) {
        const int par  = it & 1;
        const int par1 = (it - 1) & 1;
        u64* gspA = gsA + par * NBLK;
        u64* gspB = gsB + par * NBLK;

        // ===== A: update + publish (RT goes in flight) =====
        u64 keyA; UPDATE(sxyA, szA, pdA, cxA, cyA, czA, keyA);
        if (lane == 0) {
            u32 db  = (u32)(keyA >> 32);
            u32 idx = ~(u32)keyA;
            __hip_atomic_store(&redA[par][w],
                               ((u64)db << 32) | ((u64)idx << 15) | (u64)it,
                               __ATOMIC_RELAXED, __HIP_MEMORY_SCOPE_WORKGROUP);
        }
        if (w == 0) COMBINE_PUBLISH(redA, gspA, par, it);

        // ===== B: resolve it-1 (its RT expired a half-body ago) =====
        if (it > 1) {
            u64* gspB1 = gsB + par1 * NBLK;
            if (w == 0) { RESOLVE_W0(gspB1, bcB, par1, it - 1, bB, xyzB, cxB, cyB, czB); }
            else        { RESOLVE_FOLLOW(bcB, par1, it - 1, xyzB, cxB, cyB, czB); }
        }

        // ===== B: update + publish =====
        u64 keyB; UPDATE(sxyB, szB, pdB, cxB, cyB, czB, keyB);
        if (lane == 0) {
            u32 db  = (u32)(keyB >> 32);
            u32 idx = ~(u32)keyB;
            __hip_atomic_store(&redB[par][w],
                               ((u64)db << 32) | ((u64)idx << 15) | (u64)it,
                               __ATOMIC_RELAXED, __HIP_MEMORY_SCOPE_WORKGROUP);
        }
        if (w == 0) COMBINE_PUBLISH(redB, gspB, par, it);

        // ===== A: resolve it (RT hid under B's update) =====
        if (w == 0) { RESOLVE_W0(gspA, bcA, par, it, bA, xyzA, cxA, cyA, czA); }
        else        { RESOLVE_FOLLOW(bcA, par, it, xyzA, cxA, cyA, czA); }
    }

    // ===== B: final resolve (it = NSAMP-1) — only the out-writer needs it ====
    if (chunk == 0 && w == 0) {
        u64* gspB1 = gsB + ((NSAMP - 1) & 1) * NBLK;
        u64 v; bool ok;
        do {
            v  = (lane < NBLK)
                   ? __hip_atomic_load(&gspB1[lane], __ATOMIC_RELAXED,
                                       __HIP_MEMORY_SCOPE_AGENT)
                   : 0ull;
            ok = (lane < NBLK) ? ((v & 0x7FFFull) == (u64)(NSAMP - 1)) : true;
        } while (__ballot(ok) != ~0ull);
        u64 k3 = 0ull;
        if (lane < NBLK) {
            u32 db  = (u32)(v >> 32);
            u32 idx = (u32)((v >> 15) & 0x1FFFFu);
            k3 = ((u64)db << 32) | (u64)(~idx);
        }
#pragma unroll
        for (int off = 1; off <= 32; off <<= 1) {
            u64 o = __shfl_xor(k3, off, 64);
            k3 = k3 > o ? k3 : o;
        }
        if (lane == 0) out[bB * NSAMP + (NSAMP - 1)] = (int)(~(u32)k3);
    }
}

extern "C" void kernel_launch(void* const* d_in, const int* in_sizes, int n_in,
                              void* d_out, int out_size, void* d_ws, size_t ws_size,
                              hipStream_t stream) {
    const float* xyz = (const float*)d_in[0];
    int* out = (int*)d_out;
    u64* gslot = (u64*)d_ws;   // [NPAIR][2 batches][2 par][NBLK] u64 = 8 KB

    hipLaunchKernelGGL(fps_init_kernel, dim3(4), dim3(256), 0, stream, gslot);
    hipLaunchKernelGGL(fps_kernel, dim3(NPAIR * NBLK), dim3(TPB), 0, stream,
                       xyz, out, gslot);
}

// Round 13
// 9017.328 us; speedup vs baseline: 1.5086x; 1.5086x over previous
//
#include <hip/hip_runtime.h>
#include <stdint.h>

// Problem: D-FPS. points_xyz (16, 131072, 3) fp32 -> indices (16, 4096) int32.
//
// Round 13 = round 8 (best: 9603 us) with ONE removal-only change:
// the intra-block red tag-poll is replaced by __syncthreads(). red words are
// now plain key-format LDS (no tag/parity/pack), combined by w0 after the
// barrier. bc fanout loses its parity ring (safe: w0 can't write bc(it+1)
// until all followers passed barrier(it+1), which follows their bc(it) read).
// Cross-block gs protocol byte-identical to r8.
//
// Locked-in lessons (r2-r12):
//  - relaxed-only AGENT atomics; tag+payload in one 64-bit word (r7/r8:
//    agent acquire/release = chip-wide cache-maintenance storms).
//  - ONE relaxed polling wave per block (r5/r10: more pollers = 2-10x slower).
//  - points in LDS SoA; allocator never keeps them register-resident (r3-r5).
//  - FMA-chain distance d = fma(dz,dz, fma(dy,dy, dx*dx)), subs exact-rounded
//    (r2: bit-exact vs reference trajectory).
//  - batches are independent and already CU-parallel; do not pipeline them
//    into each other's critical path (r12).
//  - micro-rearrangements of the chain regress; only removals help (r9-r11).

#define BATCH 16
#define NPTS  131072
#define NSAMP 4096
#define NBLK  16                  // blocks per batch
#define TPB   1024                // 16 waves
#define CHUNK (NPTS / NBLK)       // 8192 points per block
#define PPT   (CHUNK / TPB)       // 8 points per thread
#define NWAVE (TPB / 64)

typedef unsigned long long u64;
typedef unsigned int u32;

// Global slot word (8B, one per block per parity):
//   [63:32] dist bits (>=0 -> monotone) | [31:15] idx (17b) | [14:0] iter tag
// Poison 0xAA.. -> tag 0x2AAA; zero-init -> tag 0; live tags are 1..4095.
// Ring-2 by parity; ordering via the value-dependence chain (r8-proven).

__global__ void fps_init_kernel(u64* __restrict__ ws) {
    int i = blockIdx.x * blockDim.x + threadIdx.x;
    if (i < BATCH * 2 * NBLK) ws[i] = 0ull;
}

__global__ __launch_bounds__(TPB, 4) void fps_kernel(
        const float* __restrict__ xyz, int* __restrict__ out,
        u64* __restrict__ gslot) {
    const int blk   = blockIdx.x;
    const int b     = blk & 15;    // batch: a batch's 16 blocks share blk%8
    const int chunk = blk >> 4;    //        -> same XCD (round-robin dispatch)
    const int tid   = threadIdx.x;
    const int w     = tid >> 6;
    const int lane  = tid & 63;

    const float* bxyz = xyz + (size_t)b * NPTS * 3;
    const int base = chunk * CHUNK;

    // ---- LDS: SoA points + plain red keys + tagged bc ----
    __shared__ float2 sxy[CHUNK];          // 64 KB
    __shared__ float  szz[CHUNK];          // 32 KB
    __shared__ u64 red[NWAVE];             // plain keys (barrier-ordered)
    __shared__ u64 bc;                     // widx<<32 | it (single word)
    for (int i = tid; i < CHUNK; i += TPB) {
        size_t p = (size_t)(base + i) * 3;
        sxy[i] = make_float2(bxyz[p + 0], bxyz[p + 1]);
        szz[i] = bxyz[p + 2];
    }
    if (tid == 0) bc = ~0ull;                       // low32 invalid (never an it)
    if (tid == 0 && chunk == 0) out[b * NSAMP] = 0; // iter 0 emits index 0
    __syncthreads();   // staging + bc-init visibility

    float pd[PPT];
#pragma unroll
    for (int k = 0; k < PPT; ++k) pd[k] = __builtin_inff();

    float cx = bxyz[0], cy = bxyz[1], cz = bxyz[2];

    u64* gs = gslot + (size_t)b * 2 * NBLK;   // [2][NBLK]

    for (int it = 1; it < NSAMP; ++it) {
        const int par = it & 1;
        u64* gsp = gs + par * NBLK;

        // ---- update min-dists + local argmax (LDS + registers) ----
        // Verified arithmetic (round 2, absmax 0): FMA-contracted
        //   d = fma(dz,dz, fma(dy,dy, dx*dx)), subs exact-rounded.
        float bd = -1.0f;
        int   bk = 0;
#pragma unroll
        for (int k = 0; k < PPT; ++k) {
            int i = tid + TPB * k;
            float2 xy = sxy[i];
            float  z  = szz[i];
            float dx = __fsub_rn(xy.x, cx);
            float dy = __fsub_rn(xy.y, cy);
            float dz = __fsub_rn(z,    cz);
            float d  = __builtin_fmaf(dz, dz,
                         __builtin_fmaf(dy, dy, __fmul_rn(dx, dx)));
            float nd = fminf(pd[k], d);
            pd[k] = nd;
            // strict >: earliest k wins (gi ascends with k) = first-occurrence
            if (nd > bd) { bd = nd; bk = k; }
        }
        u32 gi = (u32)(base + tid + TPB * bk);
        u64 key = ((u64)__float_as_uint(bd) << 32) | (u64)(~gi);

        // ---- wave butterfly (max dist, then min index) ----
#pragma unroll
        for (int off = 1; off <= 32; off <<= 1) {
            u64 o = __shfl_xor(key, off, 64);
            key = key > o ? key : o;
        }
        if (lane == 0) red[w] = key;      // plain store; barrier orders it
        __syncthreads();                   // replaces the red tag-poll

        if (w == 0) {
            // ---- combine 16 plain keys (real keys > 0; lanes 16+ feed 0) ----
            u64 k2 = (lane < NWAVE) ? red[lane] : 0ull;
#pragma unroll
            for (int off = 1; off <= 8; off <<= 1) {
                u64 o = __shfl_xor(k2, off, 64);
                k2 = k2 > o ? k2 : o;
            }
            // ---- ONE relaxed agent store publishes the block winner ----
            if (lane == 0) {
                u32 db  = (u32)(k2 >> 32);
                u32 idx = ~(u32)k2;        // = gi (fits 17 bits)
                __hip_atomic_store(&gsp[chunk],
                                   ((u64)db << 32) | ((u64)idx << 15) | (u64)it,
                                   __ATOMIC_RELAXED, __HIP_MEMORY_SCOPE_AGENT);
            }
            // ---- relaxed poll of the 16 slot words (byte-identical to r8) ----
            u64 v; bool ok;
            do {
                v  = (lane < NBLK)
                       ? __hip_atomic_load(&gsp[lane], __ATOMIC_RELAXED,
                                           __HIP_MEMORY_SCOPE_AGENT)
                       : 0ull;
                ok = (lane < NBLK) ? ((v & 0x7FFFull) == (u64)it) : true;
            } while (__ballot(ok) != ~0ull);
            u64 k3 = 0ull;
            if (lane < NBLK) {
                u32 db  = (u32)(v >> 32);
                u32 idx = (u32)((v >> 15) & 0x1FFFFu);
                k3 = ((u64)db << 32) | (u64)(~idx);
            }
#pragma unroll
            for (int off = 1; off <= 32; off <<= 1) {  // winner on ALL 64 lanes
                u64 o = __shfl_xor(k3, off, 64);
                k3 = k3 > o ? k3 : o;
            }
            u32 widx = ~(u32)k3;
            if (lane == 0) {
                if (chunk == 0) out[b * NSAMP + it] = (int)widx;
                __hip_atomic_store(&bc, ((u64)widx << 32) | (u64)(u32)it,
                                   __ATOMIC_RELAXED, __HIP_MEMORY_SCOPE_WORKGROUP);
            }
            // coords: same-address broadcast load (L1/L2)
            cx = bxyz[3 * (size_t)widx + 0];
            cy = bxyz[3 * (size_t)widx + 1];
            cz = bxyz[3 * (size_t)widx + 2];
        } else {
            // ---- other waves: wait for tagged LDS broadcast ----
            u64 bv;
            do {
                bv = __hip_atomic_load(&bc, __ATOMIC_RELAXED,
                                       __HIP_MEMORY_SCOPE_WORKGROUP);
            } while ((u32)bv != (u32)it);
            u32 widx = (u32)(bv >> 32);
            cx = bxyz[3 * (size_t)widx + 0];
            cy = bxyz[3 * (size_t)widx + 1];
            cz = bxyz[3 * (size_t)widx + 2];
        }
    }
}

extern "C" void kernel_launch(void* const* d_in, const int* in_sizes, int n_in,
                              void* d_out, int out_size, void* d_ws, size_t ws_size,
                              hipStream_t stream) {
    const float* xyz = (const float*)d_in[0];
    int* out = (int*)d_out;
    u64* gslot = (u64*)d_ws;   // [BATCH][2][NBLK] u64 = 4 KB

    hipLaunchKernelGGL(fps_init_kernel, dim3(1), dim3(512), 0, stream, gslot);
    hipLaunchKernelGGL(fps_kernel, dim3(BATCH * NBLK), dim3(TPB), 0, stream,
                       xyz, out, gslot);
}

// Round 14
// 8831.696 us; speedup vs baseline: 1.5403x; 1.0210x over previous
//
#include <hip/hip_runtime.h>
#include <stdint.h>

// Problem: D-FPS. points_xyz (16, 131072, 3) fp32 -> indices (16, 4096) int32.
//
// Round 14 = round 13 (best: 9017 us) with the SECOND software spin removed:
// the tagged bc fanout loop is replaced by a second __syncthreads(). bc is a
// plain LDS word (no tag): barrier2 orders w0's write before all reads; the
// next write happens after barrier1(it+1), which follows every reader's
// bc(it) read -> no WAR hazard, no ring. Secondary trim: final poll butterfly
// = 4 steps over lanes 0..15 + broadcast (was 6 full-width steps).
// gs cross-block protocol byte-identical to r8/r13 (relaxed, tagged, ring-2).
//
// Locked-in lessons (r2-r13):
//  - relaxed-only AGENT atomics; tag+payload in one 64-bit word (r7/r8:
//    agent acquire/release = chip-wide cache-maintenance storms).
//  - ONE relaxed polling wave per block (r5/r10).
//  - hardware barrier beats software tag-spin for intra-block ordering (r13).
//  - points in LDS SoA; allocator never keeps them register-resident (r3-r5).
//  - FMA-chain distance d = fma(dz,dz, fma(dy,dy, dx*dx)), subs exact-rounded
//    (r2: bit-exact vs reference trajectory).
//  - removals help; rearrangements and added traffic regress (r9-r12).

#define BATCH 16
#define NPTS  131072
#define NSAMP 4096
#define NBLK  16                  // blocks per batch
#define TPB   1024                // 16 waves
#define CHUNK (NPTS / NBLK)       // 8192 points per block
#define PPT   (CHUNK / TPB)       // 8 points per thread
#define NWAVE (TPB / 64)

typedef unsigned long long u64;
typedef unsigned int u32;

// Global slot word (8B, one per block per parity):
//   [63:32] dist bits (>=0 -> monotone) | [31:15] idx (17b) | [14:0] iter tag
// Poison 0xAA.. -> tag 0x2AAA; zero-init -> tag 0; live tags are 1..4095.
// Ring-2 by parity; ordering via the value-dependence chain (r8-proven).

__global__ void fps_init_kernel(u64* __restrict__ ws) {
    int i = blockIdx.x * blockDim.x + threadIdx.x;
    if (i < BATCH * 2 * NBLK) ws[i] = 0ull;
}

__global__ __launch_bounds__(TPB, 4) void fps_kernel(
        const float* __restrict__ xyz, int* __restrict__ out,
        u64* __restrict__ gslot) {
    const int blk   = blockIdx.x;
    const int b     = blk & 15;    // batch: a batch's 16 blocks share blk%8
    const int chunk = blk >> 4;    //        -> same XCD (round-robin dispatch)
    const int tid   = threadIdx.x;
    const int w     = tid >> 6;
    const int lane  = tid & 63;

    const float* bxyz = xyz + (size_t)b * NPTS * 3;
    const int base = chunk * CHUNK;

    // ---- LDS: SoA points + plain red keys + plain bc (all barrier-ordered) --
    __shared__ float2 sxy[CHUNK];          // 64 KB
    __shared__ float  szz[CHUNK];          // 32 KB
    __shared__ u64 red[NWAVE];
    __shared__ u32 bc;                     // winning index, barrier-ordered
    for (int i = tid; i < CHUNK; i += TPB) {
        size_t p = (size_t)(base + i) * 3;
        sxy[i] = make_float2(bxyz[p + 0], bxyz[p + 1]);
        szz[i] = bxyz[p + 2];
    }
    if (tid == 0 && chunk == 0) out[b * NSAMP] = 0; // iter 0 emits index 0
    __syncthreads();   // staging visibility

    float pd[PPT];
#pragma unroll
    for (int k = 0; k < PPT; ++k) pd[k] = __builtin_inff();

    float cx = bxyz[0], cy = bxyz[1], cz = bxyz[2];

    u64* gs = gslot + (size_t)b * 2 * NBLK;   // [2][NBLK]

    for (int it = 1; it < NSAMP; ++it) {
        const int par = it & 1;
        u64* gsp = gs + par * NBLK;

        // ---- update min-dists + local argmax (LDS + registers) ----
        // Verified arithmetic (round 2, absmax 0): FMA-contracted
        //   d = fma(dz,dz, fma(dy,dy, dx*dx)), subs exact-rounded.
        float bd = -1.0f;
        int   bk = 0;
#pragma unroll
        for (int k = 0; k < PPT; ++k) {
            int i = tid + TPB * k;
            float2 xy = sxy[i];
            float  z  = szz[i];
            float dx = __fsub_rn(xy.x, cx);
            float dy = __fsub_rn(xy.y, cy);
            float dz = __fsub_rn(z,    cz);
            float d  = __builtin_fmaf(dz, dz,
                         __builtin_fmaf(dy, dy, __fmul_rn(dx, dx)));
            float nd = fminf(pd[k], d);
            pd[k] = nd;
            // strict >: earliest k wins (gi ascends with k) = first-occurrence
            if (nd > bd) { bd = nd; bk = k; }
        }
        u32 gi = (u32)(base + tid + TPB * bk);
        u64 key = ((u64)__float_as_uint(bd) << 32) | (u64)(~gi);

        // ---- wave butterfly (max dist, then min index) ----
#pragma unroll
        for (int off = 1; off <= 32; off <<= 1) {
            u64 o = __shfl_xor(key, off, 64);
            key = key > o ? key : o;
        }
        if (lane == 0) red[w] = key;      // plain store; barrier1 orders it
        __syncthreads();                   // barrier1 (replaced red tag-poll, r13)

        if (w == 0) {
            // ---- combine 16 plain keys (real keys > 0; lanes 16+ feed 0) ----
            u64 k2 = (lane < NWAVE) ? red[lane] : 0ull;
#pragma unroll
            for (int off = 1; off <= 8; off <<= 1) {
                u64 o = __shfl_xor(k2, off, 64);
                k2 = k2 > o ? k2 : o;
            }
            // ---- ONE relaxed agent store publishes the block winner ----
            if (lane == 0) {
                u32 db  = (u32)(k2 >> 32);
                u32 idx = ~(u32)k2;        // = gi (fits 17 bits)
                __hip_atomic_store(&gsp[chunk],
                                   ((u64)db << 32) | ((u64)idx << 15) | (u64)it,
                                   __ATOMIC_RELAXED, __HIP_MEMORY_SCOPE_AGENT);
            }
            // ---- relaxed poll of the 16 slot words (byte-identical to r8) ----
            u64 v; bool ok;
            do {
                v  = (lane < NBLK)
                       ? __hip_atomic_load(&gsp[lane], __ATOMIC_RELAXED,
                                           __HIP_MEMORY_SCOPE_AGENT)
                       : 0ull;
                ok = (lane < NBLK) ? ((v & 0x7FFFull) == (u64)it) : true;
            } while (__ballot(ok) != ~0ull);
            u64 k3 = 0ull;
            if (lane < NBLK) {
                u32 db  = (u32)(v >> 32);
                u32 idx = (u32)((v >> 15) & 0x1FFFFu);
                k3 = ((u64)db << 32) | (u64)(~idx);
            }
            // 4-step butterfly: lanes 0..15 are a closed hypercube; then
            // broadcast lane0's winner to the whole wave (saves 2 u64 steps).
#pragma unroll
            for (int off = 1; off <= 8; off <<= 1) {
                u64 o = __shfl_xor(k3, off, 64);
                k3 = k3 > o ? k3 : o;
            }
            k3 = __shfl(k3, 0, 64);
            u32 widx = ~(u32)k3;
            if (lane == 0) {
                if (chunk == 0) out[b * NSAMP + it] = (int)widx;
                bc = widx;                 // plain store; barrier2 orders it
            }
        }
        __syncthreads();                   // barrier2 (replaces the bc tag-spin)

        u32 widx = bc;                     // barrier-ordered plain read
        cx = bxyz[3 * (size_t)widx + 0];   // same-address broadcast load
        cy = bxyz[3 * (size_t)widx + 1];
        cz = bxyz[3 * (size_t)widx + 2];
    }
}

extern "C" void kernel_launch(void* const* d_in, const int* in_sizes, int n_in,
                              void* d_out, int out_size, void* d_ws, size_t ws_size,
                              hipStream_t stream) {
    const float* xyz = (const float*)d_in[0];
    int* out = (int*)d_out;
    u64* gslot = (u64*)d_ws;   // [BATCH][2][NBLK] u64 = 4 KB

    hipLaunchKernelGGL(fps_init_kernel, dim3(1), dim3(512), 0, stream, gslot);
    hipLaunchKernelGGL(fps_kernel, dim3(BATCH * NBLK), dim3(TPB), 0, stream,
                       xyz, out, gslot);
}